// Round 1
// baseline (83903.906 us; speedup 1.0000x reference)
//
#include <hip/hip_runtime.h>
#include <math.h>

constexpr int NB    = 64;    // batch
constexpr int NT    = 256;   // mel steps
constexpr int NU    = 256;   // text steps
constexpr int NMELc = 80;
constexpr int PREc  = 128;
constexpr int EMBc  = 15;
constexpr int NFc   = 128;
constexpr int ENCc  = 128;
constexpr int DECc  = 512;
constexpr int WMc   = 10;
constexpr int AKS   = 16;    // att_k padded stride
constexpr int KSd   = 16;    // decoder gemm K-split
constexpr int BGd   = 16;    // decoder gemm batch group
constexpr int BGE   = 8;     // encoder batch group

__device__ __forceinline__ float sigm(float x) { return 1.0f / (1.0f + expf(-x)); }
__device__ __forceinline__ float softplusf(float x) { return fmaxf(x, 0.0f) + log1pf(expf(-fabsf(x))); }

struct Src4 {
  const float *p0, *p1, *p2, *p3;
  int l0, l1, l2, l3;
  int s0, s1, s2, s3;
};

// ---------------- generic dense: Y[r][j] = bias[j] + sum_k X[r][k]*W[k][j] ----------------
template <int K, int N, int RB>
__global__ void k_dense(const float* __restrict__ X, const float* __restrict__ W,
                        const float* __restrict__ bias, float* __restrict__ Y, int R) {
  __shared__ float xs[RB][K];
  int r0 = blockIdx.x * RB;
  int tid = threadIdx.x;  // blockDim = 128
  for (int idx = tid; idx < RB * K; idx += 128) {
    int r = idx / K, k = idx % K;
    xs[r][k] = (r0 + r < R) ? X[(size_t)(r0 + r) * K + k] : 0.0f;
  }
  __syncthreads();
  int j = tid;
  if (j >= N) return;
  float acc[RB];
#pragma unroll
  for (int r = 0; r < RB; ++r) acc[r] = 0.f;
  for (int k = 0; k < K; ++k) {
    float w = W[(size_t)k * N + j];
#pragma unroll
    for (int r = 0; r < RB; ++r) acc[r] += xs[r][k] * w;
  }
  float bj = bias[j];
  for (int r = 0; r < RB; ++r)
    if (r0 + r < R) Y[(size_t)(r0 + r) * N + j] = acc[r] + bj;
}

// ---------------- embedding gather: out[b][u][c] = emb[text[u][b]][c] ----------------
__global__ void k_embed(const int* __restrict__ text, const float* __restrict__ emb,
                        float* __restrict__ out) {
  int idx = blockIdx.x * blockDim.x + threadIdx.x;
  if (idx >= NB * NU * EMBc) return;
  int c = idx % EMBc;
  int bu = idx / EMBc;
  int u = bu % NU, b = bu / NU;
  out[idx] = emb[text[u * NB + b] * EMBc + c];
}

// ---------------- merged conv weights: Weff[t][c][f] = sum_i w[i][t][c][f]*mask_i[t] ----------------
template <int CIN>
__global__ void k_weff(const float* __restrict__ w, const float* __restrict__ bb,
                       float* __restrict__ weff, float* __restrict__ beff) {
  int idx = blockIdx.x * blockDim.x + threadIdx.x;
  const int tot = 5 * CIN * NFc;
  if (idx < tot) {
    int f = idx % NFc;
    int tc = idx / NFc;
    int c = tc % CIN, t = tc / CIN;
    float m0 = (t == 2) ? 1.f : 0.f;
    float m1 = (t >= 1 && t <= 3) ? 1.f : 0.f;
    float w0 = w[((size_t)(0 * 5 + t) * CIN + c) * NFc + f];
    float w1 = w[((size_t)(1 * 5 + t) * CIN + c) * NFc + f];
    float w2 = w[((size_t)(2 * 5 + t) * CIN + c) * NFc + f];
    weff[idx] = w0 * m0 + w1 * m1 + w2;
  }
  if (idx < NFc) beff[idx] = bb[idx] + bb[NFc + idx] + bb[2 * NFc + idx];
}

// ---------------- conv stack (5-tap SAME, relu, optional residual) ----------------
template <int CIN, bool RES>
__global__ void k_conv(const float* __restrict__ x, const float* __restrict__ weff,
                       const float* __restrict__ beff, float* __restrict__ y) {
  const int UT = 8;
  __shared__ float xs[(UT + 4) * CIN];
  int b = blockIdx.y, u0 = blockIdx.x * UT;
  int tid = threadIdx.x;  // 128
  for (int idx = tid; idx < (UT + 4) * CIN; idx += 128) {
    int c = idx % CIN;
    int uu = idx / CIN;
    int u = u0 + uu - 2;
    xs[idx] = (u >= 0 && u < NU) ? x[((size_t)b * NU + u) * CIN + c] : 0.f;
  }
  __syncthreads();
  int f = tid;
  float acc[UT];
#pragma unroll
  for (int r = 0; r < UT; ++r) acc[r] = beff[f];
  for (int t = 0; t < 5; ++t)
    for (int c = 0; c < CIN; ++c) {
      float w = weff[((size_t)t * CIN + c) * NFc + f];
#pragma unroll
      for (int r = 0; r < UT; ++r) acc[r] += xs[(r + t) * CIN + c] * w;
    }
  for (int r = 0; r < UT; ++r) {
    float v = fmaxf(acc[r], 0.f);
    if (RES) v += xs[(r + 2) * CIN + f];
    y[((size_t)b * NU + u0 + r) * NFc + f] = v;
  }
}

// ---------------- decoder LSTM gemm partial (K-split) ----------------
// grid: (H/256, NB/BGd, KSd) ; block 256 ; z layout [ks][b][4H]
template <int KC>
__global__ void k_zgemm(const float* __restrict__ W, int K, int H4, Src4 S,
                        float* __restrict__ zpart) {
  __shared__ float xs[BGd * KC];
  int tid = threadIdx.x;
  int H = H4 >> 2;
  int j = blockIdx.x * 256 + tid;
  int b0 = blockIdx.y * BGd;
  int ks = blockIdx.z;
  int k0 = ks * KC;
  int kc = K - k0;
  if (kc > KC) kc = KC;
  for (int idx = tid; idx < BGd * KC; idx += 256) {
    int bi = idx / KC, kk = idx % KC;
    float v = 0.f;
    if (kk < kc) {
      int k = k0 + kk;
      int b = b0 + bi;
      if (k < S.l0)
        v = S.p0[(size_t)b * S.s0 + k];
      else {
        k -= S.l0;
        if (k < S.l1)
          v = S.p1[(size_t)b * S.s1 + k];
        else {
          k -= S.l1;
          if (k < S.l2)
            v = S.p2[(size_t)b * S.s2 + k];
          else {
            k -= S.l2;
            v = S.p3[(size_t)b * S.s3 + k];
          }
        }
      }
    }
    xs[idx] = v;
  }
  __syncthreads();
  float a0[BGd], a1[BGd], a2[BGd], a3[BGd];
#pragma unroll
  for (int i = 0; i < BGd; ++i) { a0[i] = a1[i] = a2[i] = a3[i] = 0.f; }
  const float* Wp = W + (size_t)k0 * H4 + j;
  for (int kk = 0; kk < kc; ++kk) {
    const float* wr = Wp + (size_t)kk * H4;
    float wi = wr[0], wf = wr[H], wg = wr[2 * H], wo = wr[3 * H];
    const float* xp = xs + kk;
#pragma unroll
    for (int i = 0; i < BGd; ++i) {
      float xv = xp[i * KC];
      a0[i] += wi * xv;
      a1[i] += wf * xv;
      a2[i] += wg * xv;
      a3[i] += wo * xv;
    }
  }
  float* zp = zpart + ((size_t)ks * NB + b0) * H4 + j;
#pragma unroll
  for (int i = 0; i < BGd; ++i) {
    zp[0] = a0[i];
    zp[H] = a1[i];
    zp[2 * H] = a2[i];
    zp[3 * H] = a3[i];
    zp += H4;
  }
}

// ---------------- LSTM gate (reduce K-split partials + pointwise) ----------------
__global__ void k_gate(const float* __restrict__ zpart, int H4, const float* __restrict__ bias,
                       const float* __restrict__ cprev, int cs,
                       const float* __restrict__ hprev, int hs,
                       const float* __restrict__ mask,
                       float* __restrict__ hout, float* __restrict__ cout) {
  int H = H4 >> 2;
  int id = blockIdx.x * blockDim.x + threadIdx.x;
  if (id >= NB * H) return;
  int j = id % H, b = id / H;
  const float* zp = zpart + (size_t)b * H4 + j;
  float zi = bias[j], zf = bias[H + j], zg = bias[2 * H + j], zo = bias[3 * H + j];
  for (int ks = 0; ks < KSd; ++ks) {
    const float* q = zp + (size_t)ks * NB * H4;
    zi += q[0];
    zf += q[H];
    zg += q[2 * H];
    zo += q[3 * H];
  }
  float cp = cprev[(size_t)b * cs + j];
  float hp = hprev[(size_t)b * hs + j];
  float cn = sigm(zf) * cp + sigm(zi) * tanhf(zg);
  float hn = sigm(zo) * tanhf(cn);
  float m = mask[b];
  hn = m * hn + (1.f - m) * hp;
  cn = m * cn + (1.f - m) * cp;
  hout[(size_t)b * H + j] = hn;
  cout[(size_t)b * H + j] = cn;
}

// ---------------- attention: gate attLSTM + proj + phi + context ----------------
// grid: NB blocks, 256 threads
__global__ void k_att(const float* __restrict__ zpart, const float* __restrict__ bias,
                      const float* __restrict__ acprev, int acs,
                      const float* __restrict__ ahprev, int ahs,
                      const float* __restrict__ Wp, const float* __restrict__ bp,
                      const float* __restrict__ akprev, int aks,
                      const float* __restrict__ ctx, const float* __restrict__ text_mask,
                      const float* __restrict__ melmask,
                      const float* __restrict__ awprev, int aws,
                      float* __restrict__ ah_out, float* __restrict__ ac_out,
                      float* __restrict__ ak_out, float* __restrict__ aw_out) {
  __shared__ float ah_s[DECc];
  __shared__ float red_s[256];
  __shared__ float pr_s[32];
  __shared__ float abk[3 * WMc];
  __shared__ float phi_s[NU];
  int b = blockIdx.x, tid = threadIdx.x;
  float m = melmask[b];
  // gate the attention LSTM (raw ah into LDS, blended states out)
  for (int j = tid; j < DECc; j += 256) {
    float zi = bias[j], zf = bias[DECc + j], zg = bias[2 * DECc + j], zo = bias[3 * DECc + j];
    const float* zp = zpart + (size_t)b * 4 * DECc + j;
    for (int ks = 0; ks < KSd; ++ks) {
      const float* q = zp + (size_t)ks * NB * 4 * DECc;
      zi += q[0];
      zf += q[DECc];
      zg += q[2 * DECc];
      zo += q[3 * DECc];
    }
    float cp = acprev[(size_t)b * acs + j];
    float hp = ahprev[(size_t)b * ahs + j];
    float cn = sigm(zf) * cp + sigm(zi) * tanhf(zg);
    float hraw = sigm(zo) * tanhf(cn);
    ah_s[j] = hraw;
    ah_out[(size_t)b * DECc + j] = m * hraw + (1.f - m) * hp;
    ac_out[(size_t)b * DECc + j] = m * cn + (1.f - m) * cp;
  }
  __syncthreads();
  // proj: pr[c] = bp[c] + sum_k ah_s[k]*Wp[k][c], c<30
  {
    int c = tid & 31, ch = tid >> 5;  // 8 chunks of 64
    float s = 0.f;
    if (c < 30) {
      for (int k = ch * 64; k < ch * 64 + 64; ++k) s += ah_s[k] * Wp[k * 30 + c];
    }
    red_s[ch * 32 + c] = s;
  }
  __syncthreads();
  if (tid < 30) {
    float s = bp[tid];
    for (int ch = 0; ch < 8; ++ch) s += red_s[ch * 32 + tid];
    pr_s[tid] = s;
  }
  __syncthreads();
  if (tid < WMc) {
    float kp = akprev[(size_t)b * aks + tid];
    float a_t = softplusf(pr_s[tid]);
    float b_t = softplusf(pr_s[WMc + tid]);
    float k_t = kp + softplusf(pr_s[2 * WMc + tid]);
    abk[tid] = a_t;
    abk[WMc + tid] = b_t;
    abk[2 * WMc + tid] = k_t;
    ak_out[(size_t)b * AKS + tid] = m * k_t + (1.f - m) * kp;
  }
  __syncthreads();
  // phi[u]
  {
    int u = tid;
    float s = 0.f;
#pragma unroll
    for (int g = 0; g < WMc; ++g) {
      float dd = abk[2 * WMc + g] - (float)u;
      s += abk[g] * expf(-abk[WMc + g] * dd * dd);
    }
    phi_s[u] = s * text_mask[u * NB + b];
  }
  __syncthreads();
  // w_t[d] = sum_u phi[u]*ctx[u][b][d]
  {
    int d = tid;
    float s = 0.f;
    for (int u = 0; u < NU; ++u) s += phi_s[u] * ctx[((size_t)u * NB + b) * (2 * ENCc) + d];
    float wp_ = awprev[(size_t)b * aws + d];
    aw_out[(size_t)b * (2 * ENCc) + d] = m * s + (1.f - m) * wp_;
  }
}

// ---------------- encoder BiLSTM fused step ----------------
// grid: (NB/BGE, 2 (K-half), 2 (dir)) block 128 ; gate-only final: grid (NB/BGE,1,2)
// zE: [parity][dir*2+s][b][512]   hbuf/cbuf: [dir][parity][b][128]
__global__ void k_enc(int u, int gate_only,
                      const float* __restrict__ Wf, const float* __restrict__ bf,
                      const float* __restrict__ Wb, const float* __restrict__ bb_,
                      const float* __restrict__ convt, const float* __restrict__ text_mask,
                      float* __restrict__ ctx, float* __restrict__ hbuf,
                      float* __restrict__ cbuf, float* __restrict__ zE) {
  const size_t ZES = (size_t)4 * NB * 4 * ENCc;
  __shared__ float xs[BGE][2 * ENCc];
  int tid = threadIdx.x;  // 128
  int g = blockIdx.x, s = blockIdx.y, d = blockIdx.z;
  int b0 = g * BGE;
  const float* Wd = d ? Wb : Wf;
  const float* bd = d ? bb_ : bf;
  int j = tid;
  if (u > 0) {
    int ig = u - 1;
    int upos = d ? (NU - 1 - ig) : ig;
    const float* zr = zE + (size_t)((u - 1) & 1) * ZES;
    for (int bi = 0; bi < BGE; ++bi) {
      int b = b0 + bi;
      float zi = bd[j], zf = bd[ENCc + j], zg = bd[2 * ENCc + j], zo = bd[3 * ENCc + j];
      for (int ss = 0; ss < 2; ++ss) {
        const float* q = zr + ((size_t)(d * 2 + ss) * NB + b) * 4 * ENCc + j;
        zi += q[0];
        zf += q[ENCc];
        zg += q[2 * ENCc];
        zo += q[3 * ENCc];
      }
      float cp = 0.f, hp = 0.f;
      if (u >= 2) {
        cp = cbuf[((size_t)(d * 2 + (u & 1)) * NB + b) * ENCc + j];
        hp = hbuf[((size_t)(d * 2 + (u & 1)) * NB + b) * ENCc + j];
      }
      float cn = sigm(zf) * cp + sigm(zi) * tanhf(zg);
      float hn = sigm(zo) * tanhf(cn);
      float mt = text_mask[upos * NB + b];
      hn = mt * hn + (1.f - mt) * hp;
      cn = mt * cn + (1.f - mt) * cp;
      xs[bi][ENCc + j] = hn;
      if (s == 0) {
        hbuf[((size_t)(d * 2 + ((u - 1) & 1)) * NB + b) * ENCc + j] = hn;
        cbuf[((size_t)(d * 2 + ((u - 1) & 1)) * NB + b) * ENCc + j] = cn;
        ctx[((size_t)upos * NB + b) * (2 * ENCc) + d * ENCc + j] = hn;
      }
    }
  } else {
    for (int bi = 0; bi < BGE; ++bi) xs[bi][ENCc + j] = 0.f;
  }
  if (gate_only) return;
  {
    int upos_x = d ? (NU - 1 - u) : u;
    for (int bi = 0; bi < BGE; ++bi) {
      int b = b0 + bi;
      xs[bi][j] = convt[((size_t)b * NU + upos_x) * NFc + j];
    }
  }
  __syncthreads();
  int k0 = s * ENCc;
  float a0[BGE], a1[BGE], a2[BGE], a3[BGE];
#pragma unroll
  for (int i = 0; i < BGE; ++i) { a0[i] = a1[i] = a2[i] = a3[i] = 0.f; }
  for (int kk = 0; kk < ENCc; ++kk) {
    int k = k0 + kk;
    const float* wr = Wd + (size_t)k * 4 * ENCc + j;
    float wi = wr[0], wf = wr[ENCc], wg = wr[2 * ENCc], wo = wr[3 * ENCc];
#pragma unroll
    for (int i = 0; i < BGE; ++i) {
      float xv = xs[i][k];
      a0[i] += wi * xv;
      a1[i] += wf * xv;
      a2[i] += wg * xv;
      a3[i] += wo * xv;
    }
  }
  float* zw = zE + (size_t)(u & 1) * ZES + ((size_t)(d * 2 + s) * NB + b0) * 4 * ENCc + j;
  for (int i = 0; i < BGE; ++i) {
    zw[0] = a0[i];
    zw[ENCc] = a1[i];
    zw[2 * ENCc] = a2[i];
    zw[3 * ENCc] = a3[i];
    zw += 4 * ENCc;
  }
}

// =====================================================================================
extern "C" void kernel_launch(void* const* d_in, const int* in_sizes, int n_in,
                              void* d_out, int out_size, void* d_ws, size_t ws_size,
                              hipStream_t stream) {
  const float* in_mels = (const float*)d_in[0];
  const float* mel_mask = (const float*)d_in[1];
  const int* text = (const int*)d_in[2];
  const float* text_mask = (const float*)d_in[3];
  const float* w_pre1 = (const float*)d_in[4];
  const float* b_pre1 = (const float*)d_in[5];
  const float* w_pre2 = (const float*)d_in[6];
  const float* b_pre2 = (const float*)d_in[7];
  const float* emb = (const float*)d_in[8];
  const float* conv_w0 = (const float*)d_in[9];
  const float* conv_b0 = (const float*)d_in[10];
  const float* conv_w1 = (const float*)d_in[11];
  const float* conv_b1 = (const float*)d_in[12];
  const float* conv_w2 = (const float*)d_in[13];
  const float* conv_b2 = (const float*)d_in[14];
  const float* w_bif = (const float*)d_in[15];
  const float* b_bif = (const float*)d_in[16];
  const float* w_bib = (const float*)d_in[17];
  const float* b_bib = (const float*)d_in[18];
  const float* w_att = (const float*)d_in[19];
  const float* b_att = (const float*)d_in[20];
  const float* w_proj = (const float*)d_in[21];
  const float* b_proj = (const float*)d_in[22];
  const float* w_rnn1 = (const float*)d_in[23];
  const float* b_rnn1 = (const float*)d_in[24];
  const float* w_rnn2 = (const float*)d_in[25];
  const float* b_rnn2 = (const float*)d_in[26];
  const float* w_outp = (const float*)d_in[27];
  const float* b_outp = (const float*)d_in[28];

  float* ws = (float*)d_ws;
  size_t off = 0;
  auto alloc = [&](size_t n) {
    float* p = ws + off;
    off += (n + 63) & ~(size_t)63;
    return p;
  };
  float* corr = alloc((size_t)NT * NB * PREc);
  float* embx = alloc((size_t)NB * NU * EMBc);
  float* zA = alloc((size_t)KSd * NB * 4 * DECc);  // also conv ping (conv done before decoder)
  float* zR = alloc((size_t)KSd * NB * 4 * DECc);  // also conv pong
  float* ctx = alloc((size_t)NU * NB * 2 * ENCc);  // front half also prenet tmp
  float* zE = alloc((size_t)2 * 4 * NB * 4 * ENCc);
  float* hbufE = alloc((size_t)2 * 2 * NB * ENCc);
  float* cbufE = alloc((size_t)2 * 2 * NB * ENCc);
  float* aw = alloc((size_t)2 * NB * 2 * ENCc);
  float* ak = alloc((size_t)2 * NB * AKS);
  float* ah = alloc((size_t)2 * NB * DECc);
  float* ac = alloc((size_t)2 * NB * DECc);
  float* h1 = alloc((size_t)2 * NB * DECc);
  float* c1 = alloc((size_t)2 * NB * DECc);
  float* c2 = alloc((size_t)2 * NB * DECc);
  float* outs = alloc((size_t)NT * NB * DECc);
  float* weff0 = alloc((size_t)5 * EMBc * NFc);
  float* beff0 = alloc(NFc);
  float* weff1 = alloc((size_t)5 * NFc * NFc);
  float* beff1 = alloc(NFc);
  float* weff2 = alloc((size_t)5 * NFc * NFc);
  float* beff2 = alloc(NFc);
  float* zerob = alloc(512);
  float* convA = zA;
  float* convB = zR;
  float* tmp = ctx;

  hipMemsetAsync(zerob, 0, 512 * sizeof(float), stream);

  // ---- prenet: corr = (in_mels@w1+b1)@w2+b2 ----
  k_dense<NMELc, PREc, 8><<<NT * NB / 8, 128, 0, stream>>>(in_mels, w_pre1, b_pre1, tmp, NT * NB);
  k_dense<PREc, PREc, 8><<<NT * NB / 8, 128, 0, stream>>>(tmp, w_pre2, b_pre2, corr, NT * NB);

  // ---- text conv stacks ----
  k_embed<<<(NB * NU * EMBc + 255) / 256, 256, 0, stream>>>(text, emb, embx);
  k_weff<EMBc><<<(5 * EMBc * NFc + 255) / 256, 256, 0, stream>>>(conv_w0, conv_b0, weff0, beff0);
  k_weff<NFc><<<(5 * NFc * NFc + 255) / 256, 256, 0, stream>>>(conv_w1, conv_b1, weff1, beff1);
  k_weff<NFc><<<(5 * NFc * NFc + 255) / 256, 256, 0, stream>>>(conv_w2, conv_b2, weff2, beff2);
  k_conv<EMBc, false><<<dim3(NU / 8, NB), 128, 0, stream>>>(embx, weff0, beff0, convA);
  k_conv<NFc, true><<<dim3(NU / 8, NB), 128, 0, stream>>>(convA, weff1, beff1, convB);
  k_conv<NFc, true><<<dim3(NU / 8, NB), 128, 0, stream>>>(convB, weff2, beff2, convA);

  // ---- encoder BiLSTM (fused gate-of-prev + gemm per step) ----
  for (int u = 0; u <= NU; ++u) {
    dim3 g(NB / BGE, (u == NU) ? 1 : 2, 2);
    k_enc<<<g, 128, 0, stream>>>(u, (u == NU) ? 1 : 0, w_bif, b_bif, w_bib, b_bib, convA,
                                 text_mask, ctx, hbufE, cbufE, zE);
  }

  // ---- decoder ----
  for (int t = 0; t < NT; ++t) {
    int cur = t & 1, prv = cur ^ 1;
    const float* corr_t = corr + (size_t)t * NB * PREc;
    const float* awp = t ? aw + (size_t)prv * NB * 2 * ENCc : zerob;
    int aws_ = t ? 2 * ENCc : 0;
    const float* akp = t ? ak + (size_t)prv * NB * AKS : zerob;
    int aks_ = t ? AKS : 0;
    const float* ahp = t ? ah + (size_t)prv * NB * DECc : zerob;
    int ahs_ = t ? DECc : 0;
    const float* acp = t ? ac + (size_t)prv * NB * DECc : zerob;
    int acs_ = t ? DECc : 0;
    const float* h1p = t ? h1 + (size_t)prv * NB * DECc : zerob;
    int h1s = t ? DECc : 0;
    const float* c1p = t ? c1 + (size_t)prv * NB * DECc : zerob;
    int c1s = t ? DECc : 0;
    const float* h2p = t ? outs + (size_t)(t - 1) * NB * DECc : zerob;
    int h2s = t ? DECc : 0;
    const float* c2p = t ? c2 + (size_t)prv * NB * DECc : zerob;
    int c2s = t ? DECc : 0;
    const float* mm = mel_mask + (size_t)t * NB;
    float* awc = aw + (size_t)cur * NB * 2 * ENCc;
    float* akc = ak + (size_t)cur * NB * AKS;
    float* ahc = ah + (size_t)cur * NB * DECc;
    float* acc_ = ac + (size_t)cur * NB * DECc;
    float* h1c = h1 + (size_t)cur * NB * DECc;
    float* c1c = c1 + (size_t)cur * NB * DECc;
    float* c2c = c2 + (size_t)cur * NB * DECc;
    float* h2c = outs + (size_t)t * NB * DECc;

    // attention LSTM: x = [corr_t, att_w], h = att_h  (K = 128+256+512 = 896)
    Src4 Sa{corr_t, awp, ahp, zerob, PREc, 2 * ENCc, DECc, 0, PREc, aws_, ahs_, 0};
    k_zgemm<56><<<dim3(2, NB / BGd, KSd), 256, 0, stream>>>(w_att, 896, 4 * DECc, Sa, zA);
    k_att<<<NB, 256, 0, stream>>>(zA, b_att, acp, acs_, ahp, ahs_, w_proj, b_proj, akp, aks_,
                                  ctx, text_mask, mm, awp, aws_, ahc, acc_, akc, awc);
    // rnn1: x = [corr_t, w_t, ah], h = h1  (K = 128+256+512+512 = 1408)
    Src4 S1{corr_t, awc, ahc, h1p, PREc, 2 * ENCc, DECc, DECc, PREc, 2 * ENCc, DECc, h1s};
    k_zgemm<88><<<dim3(2, NB / BGd, KSd), 256, 0, stream>>>(w_rnn1, 1408, 4 * DECc, S1, zR);
    k_gate<<<NB * DECc / 256, 256, 0, stream>>>(zR, 4 * DECc, b_rnn1, c1p, c1s, h1p, h1s, mm,
                                                h1c, c1c);
    // rnn2: x = [corr_t, w_t, h1n], h = h2 (stored in outs rows)
    Src4 S2{corr_t, awc, h1c, h2p, PREc, 2 * ENCc, DECc, DECc, PREc, 2 * ENCc, DECc, h2s};
    k_zgemm<88><<<dim3(2, NB / BGd, KSd), 256, 0, stream>>>(w_rnn2, 1408, 4 * DECc, S2, zR);
    k_gate<<<NB * DECc / 256, 256, 0, stream>>>(zR, 4 * DECc, b_rnn2, c2p, c2s, h2p, h2s, mm,
                                                h2c, c2c);
  }

  // ---- output projection ----
  k_dense<DECc, NMELc, 8><<<NT * NB / 8, 128, 0, stream>>>(outs, w_outp, b_outp, (float*)d_out,
                                                           NT * NB);
}

// Round 2
// 19396.719 us; speedup vs baseline: 4.3257x; 4.3257x over previous
//
#include <hip/hip_runtime.h>
#include <math.h>

constexpr int NB    = 64;
constexpr int NT    = 256;
constexpr int NU    = 256;
constexpr int NMELc = 80;
constexpr int PREc  = 128;
constexpr int EMBc  = 15;
constexpr int NFc   = 128;
constexpr int ENCc  = 128;
constexpr int DECc  = 512;
constexpr int WMc   = 10;
constexpr int AKS   = 16;

__device__ __forceinline__ float sigm(float x) { return 1.0f / (1.0f + expf(-x)); }
__device__ __forceinline__ float softplusf(float x) { return fmaxf(x, 0.0f) + log1pf(expf(-fabsf(x))); }

struct Src4 {
  const float *p0, *p1, *p2, *p3;
  int l0, l1, l2, l3;
  int s0, s1, s2, s3;
};
struct ZJob {
  const float* W;  // rows K x 2048 cols
  Src4 S;          // x segments covering the K rows (starting at W row 0)
  int KS;          // number of 64-row K slices
  float* zp;       // [KS][NB][2048]
};

// ---------------- generic dense: Y[r][j] = bias[j] + sum_k X[r][k]*W[k][j] ----------------
template <int K, int N, int RB>
__global__ void k_dense(const float* __restrict__ X, const float* __restrict__ W,
                        const float* __restrict__ bias, float* __restrict__ Y, int R) {
  __shared__ float xs[RB][K];
  int r0 = blockIdx.x * RB;
  int tid = threadIdx.x;  // blockDim = 128
  for (int idx = tid; idx < RB * K; idx += 128) {
    int r = idx / K, k = idx % K;
    xs[r][k] = (r0 + r < R) ? X[(size_t)(r0 + r) * K + k] : 0.0f;
  }
  __syncthreads();
  int j = tid;
  if (j >= N) return;
  float acc[RB];
#pragma unroll
  for (int r = 0; r < RB; ++r) acc[r] = 0.f;
  for (int k = 0; k < K; ++k) {
    float w = W[(size_t)k * N + j];
#pragma unroll
    for (int r = 0; r < RB; ++r) acc[r] += xs[r][k] * w;
  }
  float bj = bias[j];
  for (int r = 0; r < RB; ++r)
    if (r0 + r < R) Y[(size_t)(r0 + r) * N + j] = acc[r] + bj;
}

// ---------------- embedding gather ----------------
__global__ void k_embed(const int* __restrict__ text, const float* __restrict__ emb,
                        float* __restrict__ out) {
  int idx = blockIdx.x * blockDim.x + threadIdx.x;
  if (idx >= NB * NU * EMBc) return;
  int c = idx % EMBc;
  int bu = idx / EMBc;
  int u = bu % NU, b = bu / NU;
  out[idx] = emb[text[u * NB + b] * EMBc + c];
}

// ---------------- merged conv weights ----------------
template <int CIN>
__global__ void k_weff(const float* __restrict__ w, const float* __restrict__ bb,
                       float* __restrict__ weff, float* __restrict__ beff) {
  int idx = blockIdx.x * blockDim.x + threadIdx.x;
  const int tot = 5 * CIN * NFc;
  if (idx < tot) {
    int f = idx % NFc;
    int tc = idx / NFc;
    int c = tc % CIN, t = tc / CIN;
    float m0 = (t == 2) ? 1.f : 0.f;
    float m1 = (t >= 1 && t <= 3) ? 1.f : 0.f;
    float w0 = w[((size_t)(0 * 5 + t) * CIN + c) * NFc + f];
    float w1 = w[((size_t)(1 * 5 + t) * CIN + c) * NFc + f];
    float w2 = w[((size_t)(2 * 5 + t) * CIN + c) * NFc + f];
    weff[idx] = w0 * m0 + w1 * m1 + w2;
  }
  if (idx < NFc) beff[idx] = bb[idx] + bb[NFc + idx] + bb[2 * NFc + idx];
}

// ---------------- conv stack ----------------
template <int CIN, bool RES>
__global__ void k_conv(const float* __restrict__ x, const float* __restrict__ weff,
                       const float* __restrict__ beff, float* __restrict__ y) {
  const int UT = 8;
  __shared__ float xs[(UT + 4) * CIN];
  int b = blockIdx.y, u0 = blockIdx.x * UT;
  int tid = threadIdx.x;  // 128
  for (int idx = tid; idx < (UT + 4) * CIN; idx += 128) {
    int c = idx % CIN;
    int uu = idx / CIN;
    int u = u0 + uu - 2;
    xs[idx] = (u >= 0 && u < NU) ? x[((size_t)b * NU + u) * CIN + c] : 0.f;
  }
  __syncthreads();
  int f = tid;
  float acc[UT];
#pragma unroll
  for (int r = 0; r < UT; ++r) acc[r] = beff[f];
  for (int t = 0; t < 5; ++t)
    for (int c = 0; c < CIN; ++c) {
      float w = weff[((size_t)t * CIN + c) * NFc + f];
#pragma unroll
      for (int r = 0; r < UT; ++r) acc[r] += xs[(r + t) * CIN + c] * w;
    }
  for (int r = 0; r < UT; ++r) {
    float v = fmaxf(acc[r], 0.f);
    if (RES) v += xs[(r + 2) * CIN + f];
    y[((size_t)b * NU + u0 + r) * NFc + f] = v;
  }
}

// ---------------- decoder GEMM partial, float4 weights, 2 jobs per launch ----------------
// block: 256 thr (4 cols/thread -> 1024 cols, cc selects half); 8 batches; KC=64 rows
__global__ __launch_bounds__(256) void k_zgemm2(ZJob j0, ZJob j1, int nb0) {
  __shared__ float xs[8][64];
  int bid = blockIdx.x;
  ZJob J = j0;
  if (bid >= nb0) {
    J = j1;
    bid -= nb0;
  }
  int KS = J.KS;
  int ks = bid % KS;
  int bg = (bid / KS) & 7;
  int cc = bid / (KS * 8);
  int tid = threadIdx.x;
  int b0 = bg * 8;
  int k0 = ks * 64;
  for (int idx = tid; idx < 8 * 64; idx += 256) {
    int bi = idx >> 6, kk = idx & 63;
    int k = k0 + kk, b = b0 + bi;
    const Src4& S = J.S;
    float v;
    if (k < S.l0)
      v = S.p0[(size_t)b * S.s0 + k];
    else {
      k -= S.l0;
      if (k < S.l1)
        v = S.p1[(size_t)b * S.s1 + k];
      else {
        k -= S.l1;
        if (k < S.l2)
          v = S.p2[(size_t)b * S.s2 + k];
        else {
          k -= S.l2;
          v = S.p3[(size_t)b * S.s3 + k];
        }
      }
    }
    xs[bi][kk] = v;
  }
  __syncthreads();
  float4 acc[8];
#pragma unroll
  for (int bi = 0; bi < 8; ++bi) acc[bi] = make_float4(0.f, 0.f, 0.f, 0.f);
  const float4* Wp = (const float4*)J.W + (size_t)k0 * 512 + cc * 256 + tid;
#pragma unroll 8
  for (int kk = 0; kk < 64; ++kk) {
    float4 w = Wp[(size_t)kk * 512];
#pragma unroll
    for (int bi = 0; bi < 8; ++bi) {
      float xv = xs[bi][kk];
      acc[bi].x += w.x * xv;
      acc[bi].y += w.y * xv;
      acc[bi].z += w.z * xv;
      acc[bi].w += w.w * xv;
    }
  }
  float4* zp = (float4*)J.zp + (size_t)(ks * 64 + b0) * 512 + cc * 256 + tid;
#pragma unroll
  for (int bi = 0; bi < 8; ++bi) zp[(size_t)bi * 512] = acc[bi];
}

// ---------------- LSTM gate (reduce K-split partials + pointwise), H=512 ----------------
__global__ __launch_bounds__(256) void k_gate(const float* __restrict__ zpart, int KS,
                                              const float* __restrict__ bias,
                                              const float* __restrict__ cprev, int cs,
                                              const float* __restrict__ hprev, int hs,
                                              const float* __restrict__ mask,
                                              float* __restrict__ hout, float* __restrict__ cout) {
  int id = blockIdx.x * 256 + threadIdx.x;
  int j = id & 511, b = id >> 9;
  const float* zp = zpart + (size_t)b * 2048 + j;
  float zi = bias[j], zf = bias[512 + j], zg = bias[1024 + j], zo = bias[1536 + j];
  for (int ks = 0; ks < KS; ++ks) {
    const float* q = zp + (size_t)ks * NB * 2048;
    zi += q[0];
    zf += q[512];
    zg += q[1024];
    zo += q[1536];
  }
  float cp = cprev[(size_t)b * cs + j];
  float hp = hprev[(size_t)b * hs + j];
  float cn = sigm(zf) * cp + sigm(zi) * tanhf(zg);
  float hn = sigm(zo) * tanhf(cn);
  float m = mask[b];
  hout[(size_t)b * 512 + j] = m * hn + (1.f - m) * hp;
  cout[(size_t)b * 512 + j] = m * cn + (1.f - m) * cp;
}

// ---------------- merged: gate2(t) [blocks < nbg] + attention step (t+1) [64 blocks] ----------------
__global__ __launch_bounds__(256) void k_attD(
    int nbg, int has_att,
    const float* __restrict__ zR, int KSr, const float* __restrict__ bR,
    const float* __restrict__ c2p, int c2s, const float* __restrict__ h2p, int h2s,
    const float* __restrict__ mmg, float* __restrict__ h2out, float* __restrict__ c2out,
    const float* __restrict__ zA, int KSa, const float* __restrict__ bA,
    const float* __restrict__ acp, int acs, const float* __restrict__ ahp, int ahs,
    const float* __restrict__ Wpj, const float* __restrict__ bpj,
    const float* __restrict__ akp, int aks,
    const float* __restrict__ ctx, const float* __restrict__ text_mask,
    const float* __restrict__ mma, const float* __restrict__ awp, int aws,
    float* __restrict__ ah_out, float* __restrict__ ac_out,
    float* __restrict__ ak_out, float* __restrict__ aw_out) {
  int tid = threadIdx.x;
  if ((int)blockIdx.x < nbg) {
    int id = blockIdx.x * 256 + tid;
    int j = id & 511, b = id >> 9;
    const float* zp = zR + (size_t)b * 2048 + j;
    float zi = bR[j], zf = bR[512 + j], zg = bR[1024 + j], zo = bR[1536 + j];
    for (int ks = 0; ks < KSr; ++ks) {
      const float* q = zp + (size_t)ks * NB * 2048;
      zi += q[0];
      zf += q[512];
      zg += q[1024];
      zo += q[1536];
    }
    float cp = c2p[(size_t)b * c2s + j];
    float hp = h2p[(size_t)b * h2s + j];
    float cn = sigm(zf) * cp + sigm(zi) * tanhf(zg);
    float hn = sigm(zo) * tanhf(cn);
    float m = mmg[b];
    h2out[(size_t)b * 512 + j] = m * hn + (1.f - m) * hp;
    c2out[(size_t)b * 512 + j] = m * cn + (1.f - m) * cp;
    return;
  }
  if (!has_att) return;
  __shared__ float ah_s[512];
  __shared__ float red_s[256];
  __shared__ float pr_s[32];
  __shared__ float abk[96];
  __shared__ float phi_s[NU];
  int b = blockIdx.x - nbg;
  float m = mma[b];
  for (int j = tid; j < 512; j += 256) {
    float zi = bA[j], zf = bA[512 + j], zg = bA[1024 + j], zo = bA[1536 + j];
    const float* zp = zA + (size_t)b * 2048 + j;
    for (int ks = 0; ks < KSa; ++ks) {
      const float* q = zp + (size_t)ks * NB * 2048;
      zi += q[0];
      zf += q[512];
      zg += q[1024];
      zo += q[1536];
    }
    float cp = acp[(size_t)b * acs + j];
    float hp = ahp[(size_t)b * ahs + j];
    float cn = sigm(zf) * cp + sigm(zi) * tanhf(zg);
    float hraw = sigm(zo) * tanhf(cn);
    ah_s[j] = hraw;
    ah_out[(size_t)b * 512 + j] = m * hraw + (1.f - m) * hp;
    ac_out[(size_t)b * 512 + j] = m * cn + (1.f - m) * cp;
  }
  __syncthreads();
  {
    int c = tid & 31, ch = tid >> 5;
    float s = 0.f;
    if (c < 30)
      for (int k = ch * 64; k < ch * 64 + 64; ++k) s += ah_s[k] * Wpj[k * 30 + c];
    red_s[ch * 32 + c] = s;
  }
  __syncthreads();
  if (tid < 30) {
    float s = bpj[tid];
    for (int ch = 0; ch < 8; ++ch) s += red_s[ch * 32 + tid];
    pr_s[tid] = s;
  }
  __syncthreads();
  if (tid < WMc) {
    float kp = akp[(size_t)b * aks + tid];
    float a_t = softplusf(pr_s[tid]);
    float b_t = softplusf(pr_s[WMc + tid]);
    float k_t = kp + softplusf(pr_s[2 * WMc + tid]);
    abk[tid] = a_t;
    abk[32 + tid] = b_t;
    abk[64 + tid] = k_t;
    ak_out[(size_t)b * AKS + tid] = m * k_t + (1.f - m) * kp;
  }
  __syncthreads();
  {
    int u = tid;
    float s = 0.f;
#pragma unroll
    for (int gg = 0; gg < WMc; ++gg) {
      float dd = abk[64 + gg] - (float)u;
      s += abk[gg] * expf(-abk[32 + gg] * dd * dd);
    }
    phi_s[u] = s * text_mask[u * NB + b];
  }
  __syncthreads();
  {
    int dcol = tid;
    float s = 0.f;
#pragma unroll 8
    for (int u = 0; u < NU; ++u) s += phi_s[u] * ctx[((size_t)u * NB + b) * 256 + dcol];
    float wprev = awp[(size_t)b * aws + dcol];
    aw_out[(size_t)b * 256 + dcol] = m * s + (1.f - m) * wprev;
  }
}

// ---------------- encoder BiLSTM fused step, float4 weights ----------------
// grid (16 bg, 4 kq, 2 dir), block 128 ; zE[par][(d*4+q)][b][512]
__global__ __launch_bounds__(128) void k_enc2(int u, int gate_only,
                                              const float* __restrict__ Wf, const float* __restrict__ bf,
                                              const float* __restrict__ Wb, const float* __restrict__ bb_,
                                              const float* __restrict__ convt,
                                              const float* __restrict__ text_mask,
                                              float* __restrict__ ctx, float* __restrict__ hbuf,
                                              float* __restrict__ cbuf, float* __restrict__ zE) {
  const size_t ZPS = (size_t)8 * NB * 512;
  __shared__ float hs[4][128];
  __shared__ float xs[4][64];
  int tid = threadIdx.x;
  int g = blockIdx.x, q = blockIdx.y, d = blockIdx.z;
  int b0 = g * 4;
  const float* Wd = d ? Wb : Wf;
  const float* bd = d ? bb_ : bf;
  int j = tid;
  if (u > 0) {
    int ig = u - 1;
    int upos = d ? (NU - 1 - ig) : ig;
    const float* zr = zE + (size_t)((u - 1) & 1) * ZPS + (size_t)d * 4 * NB * 512;
    for (int bi = 0; bi < 4; ++bi) {
      int b = b0 + bi;
      float zi = bd[j], zf = bd[128 + j], zg = bd[256 + j], zo = bd[384 + j];
      for (int qq = 0; qq < 4; ++qq) {
        const float* p = zr + ((size_t)qq * NB + b) * 512;
        zi += p[j];
        zf += p[128 + j];
        zg += p[256 + j];
        zo += p[384 + j];
      }
      float cp = 0.f, hp = 0.f;
      if (u >= 2) {
        cp = cbuf[((size_t)(d * 2 + (u & 1)) * NB + b) * 128 + j];
        hp = hbuf[((size_t)(d * 2 + (u & 1)) * NB + b) * 128 + j];
      }
      float cn = sigm(zf) * cp + sigm(zi) * tanhf(zg);
      float hn = sigm(zo) * tanhf(cn);
      float mt = text_mask[upos * NB + b];
      hn = mt * hn + (1.f - mt) * hp;
      cn = mt * cn + (1.f - mt) * cp;
      hs[bi][j] = hn;
      if (q == 0) {
        hbuf[((size_t)(d * 2 + ((u - 1) & 1)) * NB + b) * 128 + j] = hn;
        cbuf[((size_t)(d * 2 + ((u - 1) & 1)) * NB + b) * 128 + j] = cn;
        ctx[((size_t)upos * NB + b) * 256 + d * 128 + j] = hn;
      }
    }
  } else {
#pragma unroll
    for (int bi = 0; bi < 4; ++bi) hs[bi][j] = 0.f;
  }
  if (gate_only) return;
  __syncthreads();
  int k0 = q * 64;
  {
    int upos_x = d ? (NU - 1 - u) : u;
    for (int idx = tid; idx < 4 * 64; idx += 128) {
      int bi = idx >> 6, kk = idx & 63;
      int k = k0 + kk;
      float v = (k < 128) ? convt[((size_t)(b0 + bi) * NU + upos_x) * 128 + k] : hs[bi][k - 128];
      xs[bi][kk] = v;
    }
  }
  __syncthreads();
  float4 acc[4];
#pragma unroll
  for (int bi = 0; bi < 4; ++bi) acc[bi] = make_float4(0.f, 0.f, 0.f, 0.f);
  const float4* Wp = (const float4*)Wd + (size_t)k0 * 128 + tid;
#pragma unroll 8
  for (int kk = 0; kk < 64; ++kk) {
    float4 w = Wp[(size_t)kk * 128];
#pragma unroll
    for (int bi = 0; bi < 4; ++bi) {
      float xv = xs[bi][kk];
      acc[bi].x += w.x * xv;
      acc[bi].y += w.y * xv;
      acc[bi].z += w.z * xv;
      acc[bi].w += w.w * xv;
    }
  }
  float4* zw = (float4*)(zE + (size_t)(u & 1) * ZPS) + ((size_t)(d * 4 + q) * NB + b0) * 128 + tid;
#pragma unroll
  for (int bi = 0; bi < 4; ++bi) zw[(size_t)bi * 128] = acc[bi];
}

// =====================================================================================
extern "C" void kernel_launch(void* const* d_in, const int* in_sizes, int n_in,
                              void* d_out, int out_size, void* d_ws, size_t ws_size,
                              hipStream_t stream) {
  const float* in_mels = (const float*)d_in[0];
  const float* mel_mask = (const float*)d_in[1];
  const int* text = (const int*)d_in[2];
  const float* text_mask = (const float*)d_in[3];
  const float* w_pre1 = (const float*)d_in[4];
  const float* b_pre1 = (const float*)d_in[5];
  const float* w_pre2 = (const float*)d_in[6];
  const float* b_pre2 = (const float*)d_in[7];
  const float* emb = (const float*)d_in[8];
  const float* conv_w0 = (const float*)d_in[9];
  const float* conv_b0 = (const float*)d_in[10];
  const float* conv_w1 = (const float*)d_in[11];
  const float* conv_b1 = (const float*)d_in[12];
  const float* conv_w2 = (const float*)d_in[13];
  const float* conv_b2 = (const float*)d_in[14];
  const float* w_bif = (const float*)d_in[15];
  const float* b_bif = (const float*)d_in[16];
  const float* w_bib = (const float*)d_in[17];
  const float* b_bib = (const float*)d_in[18];
  const float* w_att = (const float*)d_in[19];
  const float* b_att = (const float*)d_in[20];
  const float* w_proj = (const float*)d_in[21];
  const float* b_proj = (const float*)d_in[22];
  const float* w_rnn1 = (const float*)d_in[23];
  const float* b_rnn1 = (const float*)d_in[24];
  const float* w_rnn2 = (const float*)d_in[25];
  const float* b_rnn2 = (const float*)d_in[26];
  const float* w_outp = (const float*)d_in[27];
  const float* b_outp = (const float*)d_in[28];

  float* ws = (float*)d_ws;
  size_t off = 0;
  auto alloc = [&](size_t n) {
    float* p = ws + off;
    off += (n + 63) & ~(size_t)63;
    return p;
  };
  float* corr = alloc((size_t)NT * NB * PREc);
  float* embx = alloc((size_t)NB * NU * EMBc);
  float* zR = alloc((size_t)22 * NB * 2048);   // rnn partials; also conv ping
  float* zatt = alloc((size_t)14 * NB * 2048); // att partials
  float* ctx = alloc((size_t)NU * NB * 2 * ENCc);  // also prenet tmp + conv pong
  float* zE = alloc((size_t)2 * 8 * NB * 512);
  float* hbufE = alloc((size_t)4 * NB * ENCc);
  float* cbufE = alloc((size_t)4 * NB * ENCc);
  float* aw = alloc((size_t)2 * NB * 2 * ENCc);
  float* ak = alloc((size_t)2 * NB * AKS);
  float* ah = alloc((size_t)2 * NB * DECc);
  float* ac = alloc((size_t)2 * NB * DECc);
  float* h1 = alloc((size_t)2 * NB * DECc);
  float* c1 = alloc((size_t)2 * NB * DECc);
  float* c2 = alloc((size_t)2 * NB * DECc);
  float* outs = alloc((size_t)NT * NB * DECc);
  float* weff0 = alloc((size_t)5 * EMBc * NFc);
  float* beff0 = alloc(NFc);
  float* weff1 = alloc((size_t)5 * NFc * NFc);
  float* beff1 = alloc(NFc);
  float* weff2 = alloc((size_t)5 * NFc * NFc);
  float* beff2 = alloc(NFc);
  float* zerob = alloc(1024);
  float* convA = zR;   // 2.10M <= 2.88M
  float* convB = ctx;  // 2.10M <= 4.19M, dead before ctx written
  float* tmp = ctx;

  hipMemsetAsync(zerob, 0, 1024 * sizeof(float), stream);

  // ---- prenet ----
  k_dense<NMELc, PREc, 8><<<NT * NB / 8, 128, 0, stream>>>(in_mels, w_pre1, b_pre1, tmp, NT * NB);
  k_dense<PREc, PREc, 8><<<NT * NB / 8, 128, 0, stream>>>(tmp, w_pre2, b_pre2, corr, NT * NB);

  // ---- text conv stacks ----
  k_embed<<<(NB * NU * EMBc + 255) / 256, 256, 0, stream>>>(text, emb, embx);
  k_weff<EMBc><<<(5 * EMBc * NFc + 255) / 256, 256, 0, stream>>>(conv_w0, conv_b0, weff0, beff0);
  k_weff<NFc><<<(5 * NFc * NFc + 255) / 256, 256, 0, stream>>>(conv_w1, conv_b1, weff1, beff1);
  k_weff<NFc><<<(5 * NFc * NFc + 255) / 256, 256, 0, stream>>>(conv_w2, conv_b2, weff2, beff2);
  k_conv<EMBc, false><<<dim3(NU / 8, NB), 128, 0, stream>>>(embx, weff0, beff0, convB);
  k_conv<NFc, true><<<dim3(NU / 8, NB), 128, 0, stream>>>(convB, weff1, beff1, convA);
  // note: convA=zR, convB=ctx; last conv output must live until encoder done -> put in convA,
  // but convA is also input of conv2. Swap: conv1 out convB->convA in, so conv2: convA->convB? convB=ctx gets
  // overwritten by encoder's ctx writes while still being read. Keep final output in convA (zR):
  k_conv<NFc, true><<<dim3(NU / 8, NB), 128, 0, stream>>>(convA, weff2, beff2, convB);
  // final conv result currently in convB (ctx region) — copy-free fix: run encoder reading convB is unsafe
  // (encoder writes ctx). So do one more cheap move into convA via a dense-identity is wasteful; instead
  // re-run: actually ping-pong so final lands in convA:
  // conv0: embx -> convB ; conv1: convB -> convA ; conv2: convA -> convB (above). Move convB -> convA:
  hipMemcpyAsync(convA, convB, (size_t)NB * NU * NFc * sizeof(float), hipMemcpyDeviceToDevice, stream);

  // ---- encoder BiLSTM ----
  for (int u = 0; u <= NU; ++u) {
    dim3 g(NB / 4, (u == NU) ? 1 : 4, 2);
    k_enc2<<<g, 128, 0, stream>>>(u, (u == NU) ? 1 : 0, w_bif, b_bif, w_bib, b_bib, convA,
                                  text_mask, ctx, hbufE, cbufE, zE);
  }

  // ---- decoder ----
  // pre-step: z_att(0) and att(0)
  {
    Src4 Sa0{corr, zerob, zerob, zerob, PREc, 2 * ENCc, DECc, DECc, PREc, 0, 0, 0};
    ZJob ja0{w_att, Sa0, 14, zatt};
    k_zgemm2<<<224, 256, 0, stream>>>(ja0, ja0, 224);
    k_attD<<<64, 256, 0, stream>>>(0, 1,
                                   zR, 22, b_rnn2, zerob, 0, zerob, 0, mel_mask, outs, c2,  // unused gate args
                                   zatt, 14, b_att, zerob, 0, zerob, 0, w_proj, b_proj, zerob, 0,
                                   ctx, text_mask, mel_mask, zerob, 0,
                                   ah, ac, ak, aw);  // att(0) -> parity 0
  }
  for (int t = 0; t < NT; ++t) {
    int p = t & 1, pn = p ^ 1;
    const float* corr_t = corr + (size_t)t * NB * PREc;
    const float* mm = mel_mask + (size_t)t * NB;
    float* aw_p = aw + (size_t)p * NB * 256;
    float* ak_p = ak + (size_t)p * NB * AKS;
    float* ah_p = ah + (size_t)p * NB * DECc;
    float* ac_p = ac + (size_t)p * NB * DECc;
    const float* h1p = t ? h1 + (size_t)pn * NB * DECc : zerob;
    int h1s = t ? DECc : 0;
    const float* c1p = t ? c1 + (size_t)pn * NB * DECc : zerob;
    int c1s = t ? DECc : 0;
    const float* h2p = t ? outs + (size_t)(t - 1) * NB * DECc : zerob;
    int h2s = t ? DECc : 0;
    const float* c2p = t ? c2 + (size_t)pn * NB * DECc : zerob;
    int c2s = t ? DECc : 0;
    float* h1c = h1 + (size_t)p * NB * DECc;
    float* c1c = c1 + (size_t)p * NB * DECc;
    float* c2c = c2 + (size_t)p * NB * DECc;
    float* h2c = outs + (size_t)t * NB * DECc;

    // A: z1(t) [K=1408] + z_att(t+1) [K=896]
    Src4 S1{corr_t, aw_p, ah_p, h1p, PREc, 2 * ENCc, DECc, DECc, PREc, 2 * ENCc, DECc, h1s};
    ZJob jz1{w_rnn1, S1, 22, zR};
    if (t < NT - 1) {
      const float* corr_t1 = corr + (size_t)(t + 1) * NB * PREc;
      Src4 Sa{corr_t1, aw_p, ah_p, zerob, PREc, 2 * ENCc, DECc, DECc, PREc, 2 * ENCc, DECc, 0};
      ZJob ja{w_att, Sa, 14, zatt};
      k_zgemm2<<<352 + 224, 256, 0, stream>>>(jz1, ja, 352);
    } else {
      k_zgemm2<<<352, 256, 0, stream>>>(jz1, jz1, 352);
    }
    // B: gate1
    k_gate<<<128, 256, 0, stream>>>(zR, 22, b_rnn1, c1p, c1s, h1p, h1s, mm, h1c, c1c);
    // C: z2(t) [K=1408]
    Src4 S2{corr_t, aw_p, h1c, h2p, PREc, 2 * ENCc, DECc, DECc, PREc, 2 * ENCc, DECc, h2s};
    ZJob jz2{w_rnn2, S2, 22, zR};
    k_zgemm2<<<352, 256, 0, stream>>>(jz2, jz2, 352);
    // D: gate2(t) + att(t+1)
    int has_att = (t < NT - 1) ? 1 : 0;
    const float* mma = has_att ? mel_mask + (size_t)(t + 1) * NB : mm;
    k_attD<<<128 + (has_att ? 64 : 0), 256, 0, stream>>>(
        128, has_att,
        zR, 22, b_rnn2, c2p, c2s, h2p, h2s, mm, h2c, c2c,
        zatt, 14, b_att, ac_p, DECc, ah_p, DECc, w_proj, b_proj, ak_p, AKS,
        ctx, text_mask, mma, aw_p, 2 * ENCc,
        ah + (size_t)pn * NB * DECc, ac + (size_t)pn * NB * DECc,
        ak + (size_t)pn * NB * AKS, aw + (size_t)pn * NB * 256);
  }

  // ---- output projection ----
  k_dense<DECc, NMELc, 8><<<NT * NB / 8, 128, 0, stream>>>(outs, w_outp, b_outp, (float*)d_out,
                                                           NT * NB);
}

// Round 3
// 17775.963 us; speedup vs baseline: 4.7201x; 1.0912x over previous
//
#include <hip/hip_runtime.h>
#include <math.h>

constexpr int NB    = 64;
constexpr int NT    = 256;
constexpr int NU    = 256;
constexpr int NMELc = 80;
constexpr int PREc  = 128;
constexpr int EMBc  = 15;
constexpr int NFc   = 128;
constexpr int ENCc  = 128;
constexpr int DECc  = 512;
constexpr int WMc   = 10;
constexpr int AKS   = 16;

__device__ __forceinline__ float sigm(float x) { return 1.0f / (1.0f + expf(-x)); }
__device__ __forceinline__ float softplusf(float x) { return fmaxf(x, 0.0f) + log1pf(expf(-fabsf(x))); }

struct Src4 {
  const float *p0, *p1, *p2, *p3;
  int l0, l1, l2, l3;
  int s0, s1, s2, s3;
};
struct ZJob {
  const float* W;  // K x 2048 row-major
  Src4 S;
  int KS;          // number of 64-row K slices (K = KS*64 exactly)
  float* zp;       // [KS][NB][2048]
};
struct GateJob {
  const float* zpart; int KS;
  const float* bias;
  const float* cprev; int cs;
  const float* hprev; int hs;
  const float* mask;
  float* hout; float* cout;
};

// ---------------- generic dense ----------------
template <int K, int N, int RB>
__global__ void k_dense(const float* __restrict__ X, const float* __restrict__ W,
                        const float* __restrict__ bias, float* __restrict__ Y, int R) {
  __shared__ float xs[RB][K];
  int r0 = blockIdx.x * RB;
  int tid = threadIdx.x;  // 128
  for (int idx = tid; idx < RB * K; idx += 128) {
    int r = idx / K, k = idx % K;
    xs[r][k] = (r0 + r < R) ? X[(size_t)(r0 + r) * K + k] : 0.0f;
  }
  __syncthreads();
  int j = tid;
  if (j >= N) return;
  float acc[RB];
#pragma unroll
  for (int r = 0; r < RB; ++r) acc[r] = 0.f;
  for (int k = 0; k < K; ++k) {
    float w = W[(size_t)k * N + j];
#pragma unroll
    for (int r = 0; r < RB; ++r) acc[r] += xs[r][k] * w;
  }
  float bj = bias[j];
  for (int r = 0; r < RB; ++r)
    if (r0 + r < R) Y[(size_t)(r0 + r) * N + j] = acc[r] + bj;
}

// ---------------- embedding gather ----------------
__global__ void k_embed(const int* __restrict__ text, const float* __restrict__ emb,
                        float* __restrict__ out) {
  int idx = blockIdx.x * blockDim.x + threadIdx.x;
  if (idx >= NB * NU * EMBc) return;
  int c = idx % EMBc;
  int bu = idx / EMBc;
  int u = bu % NU, b = bu / NU;
  out[idx] = emb[text[u * NB + b] * EMBc + c];
}

// ---------------- merged conv weights ----------------
template <int CIN>
__global__ void k_weff(const float* __restrict__ w, const float* __restrict__ bb,
                       float* __restrict__ weff, float* __restrict__ beff) {
  int idx = blockIdx.x * blockDim.x + threadIdx.x;
  const int tot = 5 * CIN * NFc;
  if (idx < tot) {
    int f = idx % NFc;
    int tc = idx / NFc;
    int c = tc % CIN, t = tc / CIN;
    float m0 = (t == 2) ? 1.f : 0.f;
    float m1 = (t >= 1 && t <= 3) ? 1.f : 0.f;
    float w0 = w[((size_t)(0 * 5 + t) * CIN + c) * NFc + f];
    float w1 = w[((size_t)(1 * 5 + t) * CIN + c) * NFc + f];
    float w2 = w[((size_t)(2 * 5 + t) * CIN + c) * NFc + f];
    weff[idx] = w0 * m0 + w1 * m1 + w2;
  }
  if (idx < NFc) beff[idx] = bb[idx] + bb[NFc + idx] + bb[2 * NFc + idx];
}

// ---------------- conv stack ----------------
template <int CIN, bool RES>
__global__ void k_conv(const float* __restrict__ x, const float* __restrict__ weff,
                       const float* __restrict__ beff, float* __restrict__ y) {
  const int UT = 8;
  __shared__ float xs[(UT + 4) * CIN];
  int b = blockIdx.y, u0 = blockIdx.x * UT;
  int tid = threadIdx.x;  // 128
  for (int idx = tid; idx < (UT + 4) * CIN; idx += 128) {
    int c = idx % CIN;
    int uu = idx / CIN;
    int u = u0 + uu - 2;
    xs[idx] = (u >= 0 && u < NU) ? x[((size_t)b * NU + u) * CIN + c] : 0.f;
  }
  __syncthreads();
  int f = tid;
  float acc[UT];
#pragma unroll
  for (int r = 0; r < UT; ++r) acc[r] = beff[f];
  for (int t = 0; t < 5; ++t)
    for (int c = 0; c < CIN; ++c) {
      float w = weff[((size_t)t * CIN + c) * NFc + f];
#pragma unroll
      for (int r = 0; r < UT; ++r) acc[r] += xs[(r + t) * CIN + c] * w;
    }
  for (int r = 0; r < UT; ++r) {
    float v = fmaxf(acc[r], 0.f);
    if (RES) v += xs[(r + 2) * CIN + f];
    y[((size_t)b * NU + u0 + r) * NFc + f] = v;
  }
}

// ---------------- decoder: optional gate blocks + up to 2 GEMM jobs ----------------
// GEMM block: 32 batches (bg of 2), 256 cols (nc of 8), 64 K-rows (ks of KS).
// bid layout: bg*(KS*8) + ks*8 + nc  -> bg-pair blocks 176 apart (same XCD).
__global__ __launch_bounds__(256) void k_zAB(GateJob G, int ngate, ZJob j0, int nb0, ZJob j1) {
  int tid = threadIdx.x;
  int bid = blockIdx.x;
  if (bid < ngate) {
    int id = bid * 256 + tid;
    int j = id & 511, b = id >> 9;
    const float* zp = G.zpart + (size_t)b * 2048 + j;
    float zi = G.bias[j], zf = G.bias[512 + j], zg = G.bias[1024 + j], zo = G.bias[1536 + j];
    for (int ks = 0; ks < G.KS; ++ks) {
      const float* q = zp + (size_t)ks * NB * 2048;
      zi += q[0];
      zf += q[512];
      zg += q[1024];
      zo += q[1536];
    }
    float cp = G.cprev[(size_t)b * G.cs + j];
    float hp = G.hprev[(size_t)b * G.hs + j];
    float cn = sigm(zf) * cp + sigm(zi) * tanhf(zg);
    float hn = sigm(zo) * tanhf(cn);
    float m = G.mask[b];
    G.hout[(size_t)b * 512 + j] = m * hn + (1.f - m) * hp;
    G.cout[(size_t)b * 512 + j] = m * cn + (1.f - m) * cp;
    return;
  }
  bid -= ngate;
  ZJob J = j0;
  if (bid >= nb0) {
    J = j1;
    bid -= nb0;
  }
  int KS = J.KS;
  int nc = bid & 7;
  int ks = (bid >> 3) % KS;
  int bg = bid / (KS * 8);
  __shared__ float xs[32][64];
  int k0 = ks * 64;
  for (int idx = tid; idx < 2048; idx += 256) {
    int bi = idx >> 6, kk = idx & 63;
    int k = k0 + kk, b = bg * 32 + bi;
    const Src4& S = J.S;
    float v;
    if (k < S.l0)
      v = S.p0[(size_t)b * S.s0 + k];
    else {
      k -= S.l0;
      if (k < S.l1)
        v = S.p1[(size_t)b * S.s1 + k];
      else {
        k -= S.l1;
        if (k < S.l2)
          v = S.p2[(size_t)b * S.s2 + k];
        else {
          k -= S.l2;
          v = S.p3[(size_t)b * S.s3 + k];
        }
      }
    }
    xs[bi][kk] = v;
  }
  __syncthreads();
  int bsub = tid >> 6;  // 0..3 -> batches bsub*8..bsub*8+7 within the 32
  int ct = tid & 63;
  float4 acc[8];
#pragma unroll
  for (int bi = 0; bi < 8; ++bi) acc[bi] = make_float4(0.f, 0.f, 0.f, 0.f);
  const float4* Wp = (const float4*)J.W + (size_t)k0 * 512 + nc * 64 + ct;
#pragma unroll 4
  for (int kk4 = 0; kk4 < 16; ++kk4) {
    float4 xv[8];
#pragma unroll
    for (int bi = 0; bi < 8; ++bi)
      xv[bi] = *(const float4*)&xs[bsub * 8 + bi][kk4 * 4];
#pragma unroll
    for (int q = 0; q < 4; ++q) {
      float4 w = Wp[(size_t)(kk4 * 4 + q) * 512];
#pragma unroll
      for (int bi = 0; bi < 8; ++bi) {
        float xq = (q == 0) ? xv[bi].x : (q == 1) ? xv[bi].y : (q == 2) ? xv[bi].z : xv[bi].w;
        acc[bi].x += w.x * xq;
        acc[bi].y += w.y * xq;
        acc[bi].z += w.z * xq;
        acc[bi].w += w.w * xq;
      }
    }
  }
  float4* zp = (float4*)J.zp + ((size_t)ks * 64 + bg * 32 + bsub * 8) * 512 + nc * 64 + ct;
#pragma unroll
  for (int bi = 0; bi < 8; ++bi) zp[(size_t)bi * 512] = acc[bi];
}

// ---------------- standalone gate (final step) ----------------
__global__ __launch_bounds__(256) void k_gate(const float* __restrict__ zpart, int KS,
                                              const float* __restrict__ bias,
                                              const float* __restrict__ cprev, int cs,
                                              const float* __restrict__ hprev, int hs,
                                              const float* __restrict__ mask,
                                              float* __restrict__ hout, float* __restrict__ cout) {
  int id = blockIdx.x * 256 + threadIdx.x;
  int j = id & 511, b = id >> 9;
  const float* zp = zpart + (size_t)b * 2048 + j;
  float zi = bias[j], zf = bias[512 + j], zg = bias[1024 + j], zo = bias[1536 + j];
  for (int ks = 0; ks < KS; ++ks) {
    const float* q = zp + (size_t)ks * NB * 2048;
    zi += q[0];
    zf += q[512];
    zg += q[1024];
    zo += q[1536];
  }
  float cp = cprev[(size_t)b * cs + j];
  float hp = hprev[(size_t)b * hs + j];
  float cn = sigm(zf) * cp + sigm(zi) * tanhf(zg);
  float hn = sigm(zo) * tanhf(cn);
  float m = mask[b];
  hout[(size_t)b * 512 + j] = m * hn + (1.f - m) * hp;
  cout[(size_t)b * 512 + j] = m * cn + (1.f - m) * cp;
}

// ---------------- gate1 blocks + attention step ----------------
__global__ __launch_bounds__(256) void k_attD(
    int nbg, int has_att,
    const float* __restrict__ zR, int KSr, const float* __restrict__ bR,
    const float* __restrict__ c1p, int c1s, const float* __restrict__ h1p, int h1s,
    const float* __restrict__ mmg, float* __restrict__ h1out, float* __restrict__ c1out,
    const float* __restrict__ zA, int KSa, const float* __restrict__ bA,
    const float* __restrict__ acp, int acs, const float* __restrict__ ahp, int ahs,
    const float* __restrict__ Wpj, const float* __restrict__ bpj,
    const float* __restrict__ akp, int aks,
    const float* __restrict__ ctx, const float* __restrict__ text_mask,
    const float* __restrict__ mma, const float* __restrict__ awp, int aws,
    float* __restrict__ ah_out, float* __restrict__ ac_out,
    float* __restrict__ ak_out, float* __restrict__ aw_out) {
  int tid = threadIdx.x;
  if ((int)blockIdx.x < nbg) {
    int id = blockIdx.x * 256 + tid;
    int j = id & 511, b = id >> 9;
    const float* zp = zR + (size_t)b * 2048 + j;
    float zi = bR[j], zf = bR[512 + j], zg = bR[1024 + j], zo = bR[1536 + j];
    for (int ks = 0; ks < KSr; ++ks) {
      const float* q = zp + (size_t)ks * NB * 2048;
      zi += q[0];
      zf += q[512];
      zg += q[1024];
      zo += q[1536];
    }
    float cp = c1p[(size_t)b * c1s + j];
    float hp = h1p[(size_t)b * h1s + j];
    float cn = sigm(zf) * cp + sigm(zi) * tanhf(zg);
    float hn = sigm(zo) * tanhf(cn);
    float m = mmg[b];
    h1out[(size_t)b * 512 + j] = m * hn + (1.f - m) * hp;
    c1out[(size_t)b * 512 + j] = m * cn + (1.f - m) * cp;
    return;
  }
  if (!has_att) return;
  __shared__ float ah_s[512];
  __shared__ float red_s[256];
  __shared__ float pr_s[32];
  __shared__ float abk[96];
  __shared__ float phi_s[NU];
  int b = blockIdx.x - nbg;
  float m = mma[b];
  for (int j = tid; j < 512; j += 256) {
    float zi = bA[j], zf = bA[512 + j], zg = bA[1024 + j], zo = bA[1536 + j];
    const float* zp = zA + (size_t)b * 2048 + j;
    for (int ks = 0; ks < KSa; ++ks) {
      const float* q = zp + (size_t)ks * NB * 2048;
      zi += q[0];
      zf += q[512];
      zg += q[1024];
      zo += q[1536];
    }
    float cp = acp[(size_t)b * acs + j];
    float hp = ahp[(size_t)b * ahs + j];
    float cn = sigm(zf) * cp + sigm(zi) * tanhf(zg);
    float hraw = sigm(zo) * tanhf(cn);
    ah_s[j] = hraw;
    ah_out[(size_t)b * 512 + j] = m * hraw + (1.f - m) * hp;
    ac_out[(size_t)b * 512 + j] = m * cn + (1.f - m) * cp;
  }
  __syncthreads();
  {
    int c = tid & 31, ch = tid >> 5;
    float s = 0.f;
    if (c < 30)
      for (int k = ch * 64; k < ch * 64 + 64; ++k) s += ah_s[k] * Wpj[k * 30 + c];
    red_s[ch * 32 + c] = s;
  }
  __syncthreads();
  if (tid < 30) {
    float s = bpj[tid];
    for (int ch = 0; ch < 8; ++ch) s += red_s[ch * 32 + tid];
    pr_s[tid] = s;
  }
  __syncthreads();
  if (tid < WMc) {
    float kp = akp[(size_t)b * aks + tid];
    float a_t = softplusf(pr_s[tid]);
    float b_t = softplusf(pr_s[WMc + tid]);
    float k_t = kp + softplusf(pr_s[2 * WMc + tid]);
    abk[tid] = a_t;
    abk[32 + tid] = b_t;
    abk[64 + tid] = k_t;
    ak_out[(size_t)b * AKS + tid] = m * k_t + (1.f - m) * kp;
  }
  __syncthreads();
  {
    int u = tid;
    float s = 0.f;
#pragma unroll
    for (int gg = 0; gg < WMc; ++gg) {
      float dd = abk[64 + gg] - (float)u;
      s += abk[gg] * expf(-abk[32 + gg] * dd * dd);
    }
    phi_s[u] = s * text_mask[u * NB + b];
  }
  __syncthreads();
  {
    int dcol = tid;
    float s = 0.f;
#pragma unroll 8
    for (int u = 0; u < NU; ++u) s += phi_s[u] * ctx[((size_t)u * NB + b) * 256 + dcol];
    float wprev = awp[(size_t)b * aws + dcol];
    aw_out[(size_t)b * 256 + dcol] = m * s + (1.f - m) * wprev;
  }
}

// ---------------- encoder BiLSTM fused step ----------------
__global__ __launch_bounds__(128) void k_enc2(int u, int gate_only,
                                              const float* __restrict__ Wf, const float* __restrict__ bf,
                                              const float* __restrict__ Wb, const float* __restrict__ bb_,
                                              const float* __restrict__ convt,
                                              const float* __restrict__ text_mask,
                                              float* __restrict__ ctx, float* __restrict__ hbuf,
                                              float* __restrict__ cbuf, float* __restrict__ zE) {
  const size_t ZPS = (size_t)8 * NB * 512;
  __shared__ float hs[4][128];
  __shared__ float xs[4][64];
  int tid = threadIdx.x;
  int g = blockIdx.x, q = blockIdx.y, d = blockIdx.z;
  int b0 = g * 4;
  const float* Wd = d ? Wb : Wf;
  const float* bd = d ? bb_ : bf;
  int j = tid;
  if (u > 0) {
    int ig = u - 1;
    int upos = d ? (NU - 1 - ig) : ig;
    const float* zr = zE + (size_t)((u - 1) & 1) * ZPS + (size_t)d * 4 * NB * 512;
    for (int bi = 0; bi < 4; ++bi) {
      int b = b0 + bi;
      float zi = bd[j], zf = bd[128 + j], zg = bd[256 + j], zo = bd[384 + j];
      for (int qq = 0; qq < 4; ++qq) {
        const float* p = zr + ((size_t)qq * NB + b) * 512;
        zi += p[j];
        zf += p[128 + j];
        zg += p[256 + j];
        zo += p[384 + j];
      }
      float cp = 0.f, hp = 0.f;
      if (u >= 2) {
        cp = cbuf[((size_t)(d * 2 + (u & 1)) * NB + b) * 128 + j];
        hp = hbuf[((size_t)(d * 2 + (u & 1)) * NB + b) * 128 + j];
      }
      float cn = sigm(zf) * cp + sigm(zi) * tanhf(zg);
      float hn = sigm(zo) * tanhf(cn);
      float mt = text_mask[upos * NB + b];
      hn = mt * hn + (1.f - mt) * hp;
      cn = mt * cn + (1.f - mt) * cp;
      hs[bi][j] = hn;
      if (q == 0) {
        hbuf[((size_t)(d * 2 + ((u - 1) & 1)) * NB + b) * 128 + j] = hn;
        cbuf[((size_t)(d * 2 + ((u - 1) & 1)) * NB + b) * 128 + j] = cn;
        ctx[((size_t)upos * NB + b) * 256 + d * 128 + j] = hn;
      }
    }
  } else {
#pragma unroll
    for (int bi = 0; bi < 4; ++bi) hs[bi][j] = 0.f;
  }
  if (gate_only) return;
  __syncthreads();
  int k0 = q * 64;
  {
    int upos_x = d ? (NU - 1 - u) : u;
    for (int idx = tid; idx < 4 * 64; idx += 128) {
      int bi = idx >> 6, kk = idx & 63;
      int k = k0 + kk;
      float v = (k < 128) ? convt[((size_t)(b0 + bi) * NU + upos_x) * 128 + k] : hs[bi][k - 128];
      xs[bi][kk] = v;
    }
  }
  __syncthreads();
  float4 acc[4];
#pragma unroll
  for (int bi = 0; bi < 4; ++bi) acc[bi] = make_float4(0.f, 0.f, 0.f, 0.f);
  const float4* Wp = (const float4*)Wd + (size_t)k0 * 128 + tid;
#pragma unroll 8
  for (int kk = 0; kk < 64; ++kk) {
    float4 w = Wp[(size_t)kk * 128];
#pragma unroll
    for (int bi = 0; bi < 4; ++bi) {
      float xv = xs[bi][kk];
      acc[bi].x += w.x * xv;
      acc[bi].y += w.y * xv;
      acc[bi].z += w.z * xv;
      acc[bi].w += w.w * xv;
    }
  }
  float4* zw = (float4*)(zE + (size_t)(u & 1) * ZPS) + ((size_t)(d * 4 + q) * NB + b0) * 128 + tid;
#pragma unroll
  for (int bi = 0; bi < 4; ++bi) zw[(size_t)bi * 128] = acc[bi];
}

// =====================================================================================
extern "C" void kernel_launch(void* const* d_in, const int* in_sizes, int n_in,
                              void* d_out, int out_size, void* d_ws, size_t ws_size,
                              hipStream_t stream) {
  const float* in_mels = (const float*)d_in[0];
  const float* mel_mask = (const float*)d_in[1];
  const int* text = (const int*)d_in[2];
  const float* text_mask = (const float*)d_in[3];
  const float* w_pre1 = (const float*)d_in[4];
  const float* b_pre1 = (const float*)d_in[5];
  const float* w_pre2 = (const float*)d_in[6];
  const float* b_pre2 = (const float*)d_in[7];
  const float* emb = (const float*)d_in[8];
  const float* conv_w0 = (const float*)d_in[9];
  const float* conv_b0 = (const float*)d_in[10];
  const float* conv_w1 = (const float*)d_in[11];
  const float* conv_b1 = (const float*)d_in[12];
  const float* conv_w2 = (const float*)d_in[13];
  const float* conv_b2 = (const float*)d_in[14];
  const float* w_bif = (const float*)d_in[15];
  const float* b_bif = (const float*)d_in[16];
  const float* w_bib = (const float*)d_in[17];
  const float* b_bib = (const float*)d_in[18];
  const float* w_att = (const float*)d_in[19];
  const float* b_att = (const float*)d_in[20];
  const float* w_proj = (const float*)d_in[21];
  const float* b_proj = (const float*)d_in[22];
  const float* w_rnn1 = (const float*)d_in[23];
  const float* b_rnn1 = (const float*)d_in[24];
  const float* w_rnn2 = (const float*)d_in[25];
  const float* b_rnn2 = (const float*)d_in[26];
  const float* w_outp = (const float*)d_in[27];
  const float* b_outp = (const float*)d_in[28];

  float* ws = (float*)d_ws;
  size_t off = 0;
  auto alloc = [&](size_t n) {
    float* p = ws + off;
    off += (n + 63) & ~(size_t)63;
    return p;
  };
  const size_t ZRN = (size_t)22 * NB * 2048;  // one parity of rnn partials
  float* corr = alloc((size_t)NT * NB * PREc);
  float* embx = alloc((size_t)NB * NU * EMBc);
  float* zR = alloc(2 * ZRN);                  // double-buffered rnn partials; also conv ping / prenet tmp
  float* zatt = alloc((size_t)14 * NB * 2048); // att partials
  float* ctx = alloc((size_t)NU * NB * 2 * ENCc);  // also conv pong
  float* zE = alloc((size_t)2 * 8 * NB * 512);
  float* hbufE = alloc((size_t)4 * NB * ENCc);
  float* cbufE = alloc((size_t)4 * NB * ENCc);
  float* aw = alloc((size_t)2 * NB * 2 * ENCc);
  float* ak = alloc((size_t)2 * NB * AKS);
  float* ah = alloc((size_t)2 * NB * DECc);
  float* ac = alloc((size_t)2 * NB * DECc);
  float* h1 = alloc((size_t)2 * NB * DECc);
  float* c1 = alloc((size_t)2 * NB * DECc);
  float* c2 = alloc((size_t)2 * NB * DECc);
  float* outs = alloc((size_t)NT * NB * DECc);  // h2 rows; front also conv output (encoder input)
  float* weff0 = alloc((size_t)5 * EMBc * NFc);
  float* beff0 = alloc(NFc);
  float* weff1 = alloc((size_t)5 * NFc * NFc);
  float* beff1 = alloc(NFc);
  float* weff2 = alloc((size_t)5 * NFc * NFc);
  float* beff2 = alloc(NFc);
  float* zerob = alloc(1024);
  float* convA = zR;    // ping (dead once encoder starts)
  float* convB = ctx;   // pong (dead once encoder writes ctx)
  float* convOut = outs;  // final conv result; encoder input (dead once decoder writes outs)
  float* tmp = zR;      // prenet tmp

  hipMemsetAsync(zerob, 0, 1024 * sizeof(float), stream);

  // ---- prenet ----
  k_dense<NMELc, PREc, 8><<<NT * NB / 8, 128, 0, stream>>>(in_mels, w_pre1, b_pre1, tmp, NT * NB);
  k_dense<PREc, PREc, 8><<<NT * NB / 8, 128, 0, stream>>>(tmp, w_pre2, b_pre2, corr, NT * NB);

  // ---- text conv stacks: embx -> convB -> convA -> convOut ----
  k_embed<<<(NB * NU * EMBc + 255) / 256, 256, 0, stream>>>(text, emb, embx);
  k_weff<EMBc><<<(5 * EMBc * NFc + 255) / 256, 256, 0, stream>>>(conv_w0, conv_b0, weff0, beff0);
  k_weff<NFc><<<(5 * NFc * NFc + 255) / 256, 256, 0, stream>>>(conv_w1, conv_b1, weff1, beff1);
  k_weff<NFc><<<(5 * NFc * NFc + 255) / 256, 256, 0, stream>>>(conv_w2, conv_b2, weff2, beff2);
  k_conv<EMBc, false><<<dim3(NU / 8, NB), 128, 0, stream>>>(embx, weff0, beff0, convB);
  k_conv<NFc, true><<<dim3(NU / 8, NB), 128, 0, stream>>>(convB, weff1, beff1, convA);
  k_conv<NFc, true><<<dim3(NU / 8, NB), 128, 0, stream>>>(convA, weff2, beff2, convOut);

  // ---- encoder BiLSTM ----
  for (int u = 0; u <= NU; ++u) {
    dim3 g(NB / 4, (u == NU) ? 1 : 4, 2);
    k_enc2<<<g, 128, 0, stream>>>(u, (u == NU) ? 1 : 0, w_bif, b_bif, w_bib, b_bib, convOut,
                                  text_mask, ctx, hbufE, cbufE, zE);
  }

  // ---- decoder prologue: z_att(0), att(0) ----
  GateJob Gz = {};
  Gz.zpart = zerob; Gz.KS = 0; Gz.bias = zerob; Gz.cprev = zerob; Gz.cs = 0;
  Gz.hprev = zerob; Gz.hs = 0; Gz.mask = zerob; Gz.hout = zerob; Gz.cout = zerob;
  {
    Src4 Sa0{corr, zerob, zerob, zerob, PREc, 2 * ENCc, DECc, DECc, PREc, 0, 0, 0};
    ZJob ja0{w_att, Sa0, 14, zatt};
    k_zAB<<<224, 256, 0, stream>>>(Gz, 0, ja0, 224, ja0);
    k_attD<<<64, 256, 0, stream>>>(0, 1,
                                   zR, 22, b_rnn1, zerob, 0, zerob, 0, mel_mask, h1, c1,  // unused
                                   zatt, 14, b_att, zerob, 0, zerob, 0, w_proj, b_proj, zerob, 0,
                                   ctx, text_mask, mel_mask, zerob, 0,
                                   ah, ac, ak, aw);  // att(0) -> parity 0
  }

  // ---- decoder main loop: 3 launches/step ----
  for (int t = 0; t < NT; ++t) {
    int p = t & 1, pn = p ^ 1;
    const float* corr_t = corr + (size_t)t * NB * PREc;
    const float* mm = mel_mask + (size_t)t * NB;
    float* zRp = zR + (size_t)p * ZRN;
    float* zRq = zR + (size_t)pn * ZRN;
    float* aw_p = aw + (size_t)p * NB * 256;
    float* ak_p = ak + (size_t)p * NB * AKS;
    float* ah_p = ah + (size_t)p * NB * DECc;
    float* ac_p = ac + (size_t)p * NB * DECc;

    // --- L_A: gate2(t-1) + z1(t) + z_att(t+1) ---
    Src4 S1{corr_t, aw_p, ah_p, t ? h1 + (size_t)pn * NB * DECc : zerob,
            PREc, 2 * ENCc, DECc, DECc, PREc, 2 * ENCc, DECc, t ? DECc : 0};
    ZJob j1{w_rnn1, S1, 22, zRp};
    ZJob ja = j1;
    int nb1 = 0;
    if (t < NT - 1) {
      const float* corr_t1 = corr + (size_t)(t + 1) * NB * PREc;
      Src4 Sa{corr_t1, aw_p, ah_p, zerob, PREc, 2 * ENCc, DECc, DECc, PREc, 2 * ENCc, DECc, 0};
      ja = ZJob{w_att, Sa, 14, zatt};
      nb1 = 224;
    }
    GateJob G2 = Gz;
    int ngate = 0;
    if (t > 0) {
      // gate2 for step s = t-1: reads z2 partials (parity pn), c2[(s-1)&1 = p], h2 = outs[t-2]
      ngate = 128;
      G2.zpart = zRq; G2.KS = 22; G2.bias = b_rnn2;
      G2.cprev = (t >= 2) ? c2 + (size_t)p * NB * DECc : zerob; G2.cs = (t >= 2) ? DECc : 0;
      G2.hprev = (t >= 2) ? outs + (size_t)(t - 2) * NB * DECc : zerob; G2.hs = (t >= 2) ? DECc : 0;
      G2.mask = mel_mask + (size_t)(t - 1) * NB;
      G2.hout = outs + (size_t)(t - 1) * NB * DECc;
      G2.cout = c2 + (size_t)pn * NB * DECc;
    }
    k_zAB<<<ngate + 352 + nb1, 256, 0, stream>>>(G2, ngate, j1, 352, ja);

    // --- L_B: gate1(t) + att(t+1) ---
    int has_att = (t < NT - 1) ? 1 : 0;
    const float* mma = has_att ? mel_mask + (size_t)(t + 1) * NB : mm;
    k_attD<<<128 + (has_att ? 64 : 0), 256, 0, stream>>>(
        128, has_att,
        zRp, 22, b_rnn1,
        t ? c1 + (size_t)pn * NB * DECc : zerob, t ? DECc : 0,
        t ? h1 + (size_t)pn * NB * DECc : zerob, t ? DECc : 0,
        mm, h1 + (size_t)p * NB * DECc, c1 + (size_t)p * NB * DECc,
        zatt, 14, b_att, ac_p, DECc, ah_p, DECc, w_proj, b_proj, ak_p, AKS,
        ctx, text_mask, mma, aw_p, 2 * ENCc,
        ah + (size_t)pn * NB * DECc, ac + (size_t)pn * NB * DECc,
        ak + (size_t)pn * NB * AKS, aw + (size_t)pn * NB * 256);

    // --- L_C: z2(t) ---
    Src4 S2{corr_t, aw_p, h1 + (size_t)p * NB * DECc,
            t ? outs + (size_t)(t - 1) * NB * DECc : zerob,
            PREc, 2 * ENCc, DECc, DECc, PREc, 2 * ENCc, DECc, t ? DECc : 0};
    ZJob j2{w_rnn2, S2, 22, zRp};
    k_zAB<<<352, 256, 0, stream>>>(Gz, 0, j2, 352, j2);
  }
  // final gate2(NT-1): z2 partials parity (NT-1)&1 = 1
  k_gate<<<128, 256, 0, stream>>>(zR + ZRN, 22, b_rnn2,
                                  c2, DECc, outs + (size_t)(NT - 2) * NB * DECc, DECc,
                                  mel_mask + (size_t)(NT - 1) * NB,
                                  outs + (size_t)(NT - 1) * NB * DECc, c2 + (size_t)NB * DECc);

  // ---- output projection ----
  k_dense<DECc, NMELc, 8><<<NT * NB / 8, 128, 0, stream>>>(outs, w_outp, b_outp, (float*)d_out,
                                                           NT * NB);
}